// Round 13
// baseline (218.552 us; speedup 1.0000x reference)
//
#include <hip/hip_runtime.h>
#include <hip/hip_bf16.h>

#define NN 256
#define CC 128

typedef __attribute__((ext_vector_type(8))) short bf16x8;
typedef __attribute__((ext_vector_type(4))) short bf16x4;
typedef __attribute__((ext_vector_type(4))) float f32x4;

static __device__ __forceinline__ short f2bf(float f) {
  union { float f; unsigned u; } un; un.f = f;
  unsigned r = un.u + 0x7fff + ((un.u >> 16) & 1);
  return (short)(r >> 16);
}
static __device__ __forceinline__ float bf2f(short s) {
  union { unsigned u; float f; } un;
  un.u = ((unsigned)(unsigned short)s) << 16;
  return un.f;
}

// ---------------- Kernel P: pre-pack weights to bf16 A-fragment layout ----------
__global__ void prep_kernel(const float* __restrict__ Wq, const float* __restrict__ Wk,
                            const float* __restrict__ Wv, const float* __restrict__ Wg,
                            const float* __restrict__ Wo, short* __restrict__ wpk)
{
  const int c = blockIdx.x * 256 + threadIdx.x;   // 0..10239
  const int w = c >> 11;
  const int rem = c & 2047;
  const int nt = rem >> 8;
  const int kc = (rem >> 6) & 3;
  const int lane = rem & 63;
  const float* W = (w == 0) ? Wq : (w == 1) ? Wk : (w == 2) ? Wv : (w == 3) ? Wg : Wo;
  const int row = nt * 16 + (lane & 15);
  const int col = kc * 32 + (lane >> 4) * 8;
  const float* src = W + row * CC + col;
  bf16x8 b;
  #pragma unroll
  for (int j = 0; j < 8; ++j) b[j] = f2bf(src[j]);
  *(bf16x8*)(wpk + (size_t)c * 8) = b;
}

// ---------------- Kernel A: projections, W staged in LDS ----------------
// grid 1024 = (proj, i): block does ONE projection for all 256 rows of i.
// 4 waves x 64 rows; W-frags from LDS (ds_read_b128, no global chains).
__global__ __launch_bounds__(256) void proj_kernel(
    const float* __restrict__ pair, const short* __restrict__ wpk,
    const float* __restrict__ bq, const float* __restrict__ bk,
    const float* __restrict__ bv, const float* __restrict__ bg,
    short* __restrict__ qo, short* __restrict__ ko,
    short* __restrict__ vo, short* __restrict__ go)
{
  __shared__ short Wl[16384];
  const int tid  = threadIdx.x;
  const int wid  = tid >> 6;
  const int lane = tid & 63;
  const int g    = lane >> 4;
  const int t16  = lane & 15;

  const int pj = blockIdx.x & 3;       // projection: 0=q 1=k 2=v 3=gate
  const int ib = blockIdx.x >> 2;      // i block

  // stage prepacked W -> LDS, coalesced (out_kernel-proven pattern)
  #pragma unroll
  for (int it = 0; it < 8; ++it) {
    const int c = it*256 + tid;
    *(bf16x8*)&Wl[c*8] = *(const bf16x8*)(wpk + (size_t)pj*16384 + (size_t)c*8);
  }

  const float* bias = (pj == 0) ? bq : (pj == 1) ? bk : (pj == 2) ? bv : bg;
  f32x4 bcol[8];
  #pragma unroll
  for (int nt = 0; nt < 8; ++nt) bcol[nt] = *(const f32x4*)(bias + nt*16 + g*4);
  short* outp = (pj == 0) ? qo : (pj == 1) ? ko : (pj == 2) ? vo : go;

  const int row0 = ib*256 + wid*64;

  // prologue raw loads for iter 0 (issued before the barrier for overlap)
  f32x4 rawA[8];
  {
    const float* p0 = pair + (size_t)(row0 + t16) * CC + g*8;
    #pragma unroll
    for (int kc = 0; kc < 4; ++kc) {
      rawA[kc*2]     = *(const f32x4*)(p0 + kc*32);
      rawA[kc*2 + 1] = *(const f32x4*)(p0 + kc*32 + 4);
    }
  }
  __syncthreads();

  #pragma unroll
  for (int mc = 0; mc < 4; ++mc) {
    const int m = row0 + mc*16 + t16;
    f32x4 rawB[8];
    if (mc < 3) {   // issue next-iter loads before this iter's compute
      const float* pn = pair + (size_t)(m + 16) * CC + g*8;
      #pragma unroll
      for (int kc = 0; kc < 4; ++kc) {
        rawB[kc*2]     = *(const f32x4*)(pn + kc*32);
        rawB[kc*2 + 1] = *(const f32x4*)(pn + kc*32 + 4);
      }
    }

    bf16x8 pf[4];
    #pragma unroll
    for (int kc = 0; kc < 4; ++kc) {
      bf16x8 a;
      #pragma unroll
      for (int j = 0; j < 8; ++j) a[j] = f2bf(rawA[kc*2 + (j>>2)][j&3]);
      pf[kc] = a;
    }

    f32x4 acc[8];
    #pragma unroll
    for (int nt = 0; nt < 8; ++nt) acc[nt] = f32x4{0.f,0.f,0.f,0.f};
    #pragma unroll
    for (int kc = 0; kc < 4; ++kc)
      #pragma unroll
      for (int nt = 0; nt < 8; ++nt) {
        bf16x8 wfr = *(const bf16x8*)&Wl[((nt*4 + kc)*64 + lane)*8];
        acc[nt] = __builtin_amdgcn_mfma_f32_16x16x32_bf16(wfr, pf[kc], acc[nt], 0, 0, 0);
      }

    // D[n][m]: lane owns cols nt*16+g*4+r of row m -> packed 8B stores, [m][C]
    const size_t rowoff = (size_t)m * CC;
    #pragma unroll
    for (int nt = 0; nt < 8; ++nt) {
      f32x4 v;
      #pragma unroll
      for (int r = 0; r < 4; ++r) v[r] = acc[nt][r] + bcol[nt][r];
      if (pj == 3) {
        #pragma unroll
        for (int r = 0; r < 4; ++r) v[r] = 1.f / (1.f + __expf(-v[r]));
      }
      bf16x4 pk;
      #pragma unroll
      for (int r = 0; r < 4; ++r) pk[r] = f2bf(v[r]);
      *(bf16x4*)(outp + rowoff + nt*16 + g*4) = pk;
    }

    if (mc < 3) {
      #pragma unroll
      for (int u = 0; u < 8; ++u) rawA[u] = rawB[u];
    }
  }
}

// ---------------- Kernel B: per-(i,h,qhalf) attention, 32KB LDS ------------
// grid 2048, block 256 (4 waves); wave = 32 q-rows in 2 chunks of 16.
// QK^T swapped (lane owns q-row t16's 64 scores); PV swapped via swizzled V^T/P LDS.
// No explicit LDS fences: per-wave DS ops are in-order and P is wave-private.
// ao aliases qi (safe: wave reads its Q rows before writing them; disjoint otherwise).
__global__ __launch_bounds__(256) void attn_kernel(
    const short* __restrict__ qi, const short* __restrict__ ki,
    const short* __restrict__ vi, short* __restrict__ ao)
{
  __shared__ short Vsl[32*256];    // [ch][kpos] swizzled: idx = ch*256 + (kp ^ ((ch&7)<<3))
  __shared__ short Pl[4][2048];    // per-wave [16 q][128 kp-half]: q*128 + (kp_l ^ ((q&7)<<3))

  const int bid  = blockIdx.x;
  const int qh2  = bid & 1;                 // q half (0/1)
  const int h    = (bid >> 1) & 3;
  const int i    = bid >> 3;
  const int tid  = threadIdx.x;
  const int wid  = tid >> 6, lane = tid & 63;
  const int g    = lane >> 4, t16 = lane & 15;
  const size_t mbase = (size_t)i * NN;      // row index base

  { // stage V^T (kpos = tid), scalar scatter with swizzle
    const short* vr = vi + (mbase + tid) * CC + h*32;
    #pragma unroll
    for (int u = 0; u < 4; ++u) {
      bf16x8 v8 = *(const bf16x8*)(vr + u*8);
      #pragma unroll
      for (int e = 0; e < 8; ++e) {
        const int ch = u*8 + e;
        Vsl[ch*256 + (tid ^ ((ch & 7) << 3))] = v8[e];
      }
    }
  }
  __syncthreads();

  const float cs = 0.17677669529663689f * 1.4426950408889634f; // scale * log2(e)
  const int swzP = (t16 & 7) << 3;
  const int ch0 = t16, ch1 = 16 + t16;                   // ch within head (0..31)
  const int swzV0 = (ch0 & 7) << 3, swzV1 = (ch1 & 7) << 3;
  short* Pw = &Pl[wid][0];

  #pragma unroll 1
  for (int cc = 0; cc < 2; ++cc) {
    const int q0 = qh2*128 + wid*32 + cc*16;
    bf16x8 qf = *(const bf16x8*)(qi + (mbase + q0 + t16)*CC + h*32 + g*8);

    f32x4 s[16];
    #pragma unroll
    for (int t = 0; t < 16; ++t) {
      bf16x8 kf = *(const bf16x8*)(ki + (mbase + t*16 + t16)*CC + h*32 + g*8);
      s[t] = __builtin_amdgcn_mfma_f32_16x16x32_bf16(kf, qf, f32x4{0.f,0.f,0.f,0.f}, 0, 0, 0);
    }

    // softmax for q-row q0+t16: in-lane over 64 scores + reduce across g
    f32x4 m4 = s[0];
    #pragma unroll
    for (int t = 1; t < 16; ++t)
      #pragma unroll
      for (int r = 0; r < 4; ++r) m4[r] = fmaxf(m4[r], s[t][r]);
    float mx = fmaxf(fmaxf(m4[0], m4[1]), fmaxf(m4[2], m4[3]));
    mx = fmaxf(mx, __shfl_xor(mx, 16));
    mx = fmaxf(mx, __shfl_xor(mx, 32));

    f32x4 s4 = f32x4{0.f,0.f,0.f,0.f};
    #pragma unroll
    for (int t = 0; t < 16; ++t) {
      f32x4 v = s[t];
      #pragma unroll
      for (int r = 0; r < 4; ++r) { v[r] = exp2f((v[r] - mx) * cs); s4[r] += v[r]; }
      s[t] = v;
    }
    float sum = (s4[0] + s4[1]) + (s4[2] + s4[3]);
    sum += __shfl_xor(sum, 16);
    sum += __shfl_xor(sum, 32);
    const float sm = 1.f / sum;

    f32x4 o0 = f32x4{0.f,0.f,0.f,0.f};
    f32x4 o1 = f32x4{0.f,0.f,0.f,0.f};
    #pragma unroll
    for (int half = 0; half < 2; ++half) {
      #pragma unroll
      for (int tt = 0; tt < 8; ++tt) {
        const int t = half*8 + tt;
        bf16x4 pk;
        #pragma unroll
        for (int r = 0; r < 4; ++r) pk[r] = f2bf(s[t][r]);
        *(bf16x4*)&Pw[t16*128 + ((tt*16 + g*4) ^ swzP)] = pk;
      }

      bf16x8 pa[4];
      #pragma unroll
      for (int kc = 0; kc < 4; ++kc)
        pa[kc] = *(const bf16x8*)&Pw[t16*128 + ((kc*32 + g*8) ^ swzP)];

      #pragma unroll
      for (int kc = 0; kc < 4; ++kc) {
        const int kb = half*128 + kc*32 + g*8;
        bf16x8 v0 = *(const bf16x8*)&Vsl[ch0*256 + (kb ^ swzV0)];
        bf16x8 v1 = *(const bf16x8*)&Vsl[ch1*256 + (kb ^ swzV1)];
        o0 = __builtin_amdgcn_mfma_f32_16x16x32_bf16(v0, pa[kc], o0, 0, 0, 0);
        o1 = __builtin_amdgcn_mfma_f32_16x16x32_bf16(v1, pa[kc], o1, 0, 0, 0);
      }
    }

    // D[ch][q]: lane owns 4 consecutive ch of its own q-row
    const size_t ob = (mbase + q0 + t16)*CC + h*32;
    bf16x4 pk0, pk1;
    #pragma unroll
    for (int r = 0; r < 4; ++r) { pk0[r] = f2bf(o0[r] * sm); pk1[r] = f2bf(o1[r] * sm); }
    *(bf16x4*)(ao + ob + g*4)      = pk0;
    *(bf16x4*)(ao + ob + 16 + g*4) = pk1;
  }
}

// ---------------- Kernel C: gate*attn @ Wo^T + residual + LayerNorm -------------
// grid 1024 (64 rows), block 256 (4 waves, wave = 16 rows). ALL global read
// streams (ai, gi, pair) issued before the Wl-staging barrier.
__global__ __launch_bounds__(256) void out_kernel(
    const short* __restrict__ ai, const short* __restrict__ gi,
    const short* __restrict__ wpk_o, const float* __restrict__ bo,
    const float* __restrict__ pair, const float* __restrict__ gamma,
    const float* __restrict__ beta, float* __restrict__ out)
{
  __shared__ short Wl[16384];
  const int tid = threadIdx.x;
  const int wid = tid >> 6, lane = tid & 63;
  const int g = lane >> 4, t16 = lane & 15;

  const int m0 = blockIdx.x*64 + wid*16;
  const size_t rowoff = (size_t)(m0 + t16) * CC;

  // issue ALL global loads first (overlap with LDS staging)
  bf16x8 a8[4], g8[4];
  #pragma unroll
  for (int kc = 0; kc < 4; ++kc) {
    a8[kc] = *(const bf16x8*)(ai + rowoff + kc*32 + g*8);
    g8[kc] = *(const bf16x8*)(gi + rowoff + kc*32 + g*8);
  }
  f32x4 p4[8];
  #pragma unroll
  for (int nt = 0; nt < 8; ++nt)
    p4[nt] = *(const f32x4*)(pair + rowoff + nt*16 + g*4);

  #pragma unroll
  for (int it = 0; it < 8; ++it) {   // stage prepacked Wo -> LDS, coalesced
    const int c = it*256 + tid;
    *(bf16x8*)&Wl[c*8] = *(const bf16x8*)(wpk_o + (size_t)c*8);
  }
  __syncthreads();

  bf16x8 xf[4];
  #pragma unroll
  for (int kc = 0; kc < 4; ++kc) {
    bf16x8 o;
    #pragma unroll
    for (int j = 0; j < 8; ++j) o[j] = f2bf(bf2f(a8[kc][j]) * bf2f(g8[kc][j]));
    xf[kc] = o;
  }

  f32x4 acc[8];
  #pragma unroll
  for (int nt = 0; nt < 8; ++nt) acc[nt] = f32x4{0.f,0.f,0.f,0.f};
  #pragma unroll
  for (int kc = 0; kc < 4; ++kc)
    #pragma unroll
    for (int nt = 0; nt < 8; ++nt) {
      bf16x8 wfr = *(const bf16x8*)&Wl[((nt*4 + kc)*64 + lane)*8];
      acc[nt] = __builtin_amdgcn_mfma_f32_16x16x32_bf16(wfr, xf[kc], acc[nt], 0, 0, 0);
    }

  float val[8][4];
  #pragma unroll
  for (int nt = 0; nt < 8; ++nt) {
    f32x4 b4 = *(const f32x4*)(bo + nt*16 + g*4);
    #pragma unroll
    for (int r = 0; r < 4; ++r) val[nt][r] = acc[nt][r] + b4[r] + p4[nt][r];
  }
  float sum = 0.f;
  #pragma unroll
  for (int nt = 0; nt < 8; ++nt)
    #pragma unroll
    for (int r = 0; r < 4; ++r) sum += val[nt][r];
  sum += __shfl_xor(sum, 16); sum += __shfl_xor(sum, 32);
  const float mu = sum * (1.f/128.f);
  float sq = 0.f;
  #pragma unroll
  for (int nt = 0; nt < 8; ++nt)
    #pragma unroll
    for (int r = 0; r < 4; ++r) { float d = val[nt][r] - mu; sq += d*d; }
  sq += __shfl_xor(sq, 16); sq += __shfl_xor(sq, 32);
  const float rstd = rsqrtf(sq * (1.f/128.f) + 1e-5f);

  #pragma unroll
  for (int nt = 0; nt < 8; ++nt) {
    f32x4 g4 = *(const f32x4*)(gamma + nt*16 + g*4);
    f32x4 b4 = *(const f32x4*)(beta  + nt*16 + g*4);
    f32x4 o4;
    #pragma unroll
    for (int r = 0; r < 4; ++r) o4[r] = (val[nt][r] - mu) * rstd * g4[r] + b4[r];
    *(f32x4*)(out + rowoff + nt*16 + g*4) = o4;
  }
}

extern "C" void kernel_launch(void* const* d_in, const int* in_sizes, int n_in,
                              void* d_out, int out_size, void* d_ws, size_t ws_size,
                              hipStream_t stream) {
  const float* pair  = (const float*)d_in[0];
  const float* Wq    = (const float*)d_in[1];
  const float* bq    = (const float*)d_in[2];
  const float* Wk    = (const float*)d_in[3];
  const float* bk    = (const float*)d_in[4];
  const float* Wv    = (const float*)d_in[5];
  const float* bv    = (const float*)d_in[6];
  const float* Wg    = (const float*)d_in[7];
  const float* bg    = (const float*)d_in[8];
  const float* Wo    = (const float*)d_in[9];
  const float* bo    = (const float*)d_in[10];
  const float* gamma = (const float*)d_in[11];
  const float* beta  = (const float*)d_in[12];
  float* out = (float*)d_out;

  short* wpk  = (short*)d_ws;            // 5 * 16384 bf16, prepacked weights
  short* q_ws = wpk + 81920;             // [m][C] bf16
  short* k_ws = q_ws + 8388608;
  short* v_ws = k_ws + 8388608;
  short* g_ws = v_ws + 8388608;          // [m][C] bf16 (sigmoid applied)
  short* a_ws = q_ws;                    // attn out aliases Q (proven-safe, see attn)

  hipLaunchKernelGGL(prep_kernel, dim3(40), dim3(256), 0, stream,
                     Wq, Wk, Wv, Wg, Wo, wpk);
  hipLaunchKernelGGL(proj_kernel, dim3(1024), dim3(256), 0, stream,
                     pair, wpk, bq, bk, bv, bg, q_ws, k_ws, v_ws, g_ws);
  hipLaunchKernelGGL(attn_kernel, dim3(2048), dim3(256), 0, stream,
                     q_ws, k_ws, v_ws, a_ws);
  hipLaunchKernelGGL(out_kernel, dim3(1024), dim3(256), 0, stream,
                     a_ws, g_ws, wpk + 4*16384, bo, pair, gamma, beta, out);
}